// Round 3
// baseline (1101.407 us; speedup 1.0000x reference)
//
#include <hip/hip_runtime.h>

#define B_ 2048
#define S_ 50
#define E_ 300
#define NPAIR 44850
#define KSPLIT 8
#define R_ (B_ * S_)            // 102400 rows for attn fc
#define PADSCORE (-4294967295.0f)

typedef _Float16 h8 __attribute__((ext_vector_type(8)));
typedef float f4 __attribute__((ext_vector_type(4)));

// ---------- chunk metadata: each 32-wide k-chunk has a single i, 8-aligned j0 ----------
__global__ void k_meta(int* __restrict__ meta) {
  __shared__ int cnt[304], start[304];
  int i = threadIdx.x;
  if (i < 299) {
    int js = (i + 1) & ~7;
    cnt[i] = (300 - js + 31) >> 5;
  }
  __syncthreads();
  if (threadIdx.x == 0) {
    int s = 0;
    for (int r = 0; r < 299; r++) { start[r] = s; s += cnt[r]; }
  }
  __syncthreads();
  if (i < 299) {
    int js = (i + 1) & ~7;
    for (int c = 0; c < cnt[i]; c++)
      meta[start[i] + c] = i | ((js + 32 * c) << 16);
  }
}

// ---------- Wg[e][ch*32+kk] = f16( fc7_w[e, p(i,j)] * (v_i . v_j) ), zeros on pads ----------
__global__ __launch_bounds__(256) void k_wg2(
    const float* __restrict__ w7, const float* __restrict__ v,
    const int* __restrict__ meta, _Float16* __restrict__ Wg, int kpad2) {
  int ch = blockIdx.x;
  int mt = meta[ch];
  int i = mt & 0xffff, j0 = mt >> 16;
  int kk = threadIdx.x & 31;
  int j = j0 + kk;
  bool valid = (j > i) && (j < 300);
  int p = 0;
  float g = 0.f;
  if (valid) {
    p = i * (599 - i) / 2 + (j - i - 1);
    g = v[i*4+0]*v[j*4+0] + v[i*4+1]*v[j*4+1] + v[i*4+2]*v[j*4+2] + v[i*4+3]*v[j*4+3];
  }
  #pragma unroll
  for (int rep = 0; rep < 2; rep++) {
    int e = blockIdx.y * 16 + (threadIdx.x >> 5) + rep * 8;
    float val = (valid && e < 300) ? w7[(size_t)e * NPAIR + p] * g : 0.f;
    Wg[(size_t)e * kpad2 + ch * 32 + kk] = (_Float16)val;
  }
}

// ---------- attn fc: a[r][16] = relu(x[r] @ w^T + b), sabs[r] = sum|x[r]| ----------
__global__ __launch_bounds__(256) void k_attn2(
    const float* __restrict__ x, const float* __restrict__ w1, const float* __restrict__ b1,
    const float* __restrict__ w3, const float* __restrict__ b3,
    float* __restrict__ a, float* __restrict__ sabs) {
  __shared__ float xs[128][68];
  __shared__ float wL[16][308];
  const int tid = threadIdx.x;
  const int r0 = blockIdx.x * 128;
  for (int u = tid; u < 16 * 75; u += 256) {
    int t = u / 75, q = u - t * 75;
    float4 v4 = (t < 8) ? *(const float4*)&w1[t * 300 + q * 4]
                        : *(const float4*)&w3[(t - 8) * 300 + q * 4];
    *(float4*)&wL[t][q * 4] = v4;
  }
  const int rg = tid >> 3, tg = tid & 7;
  float acc[4][2] = {};
  float sa[4] = {};
  for (int k0 = 0; k0 < 300; k0 += 64) {
    int w = min(64, 300 - k0);
    __syncthreads();
    #pragma unroll
    for (int it = 0; it < 8; it++) {
      int u = tid + it * 256;
      int r = u >> 4, q = u & 15;
      float4 v4 = {0.f, 0.f, 0.f, 0.f};
      if (q * 4 < w) v4 = *(const float4*)&x[(size_t)(r0 + r) * 300 + k0 + q * 4];
      *(float4*)&xs[r][q * 4] = v4;
    }
    __syncthreads();
    for (int q = 0; q < (w >> 2); q++) {
      float4 w0 = *(float4*)&wL[tg * 2][k0 + q * 4];
      float4 w1v = *(float4*)&wL[tg * 2 + 1][k0 + q * 4];
      #pragma unroll
      for (int k2 = 0; k2 < 4; k2++) {
        float4 xv = *(float4*)&xs[rg + 32 * k2][q * 4];
        acc[k2][0] += xv.x * w0.x + xv.y * w0.y + xv.z * w0.z + xv.w * w0.w;
        acc[k2][1] += xv.x * w1v.x + xv.y * w1v.y + xv.z * w1v.z + xv.w * w1v.w;
        if (tg == 0)
          sa[k2] += fabsf(xv.x) + fabsf(xv.y) + fabsf(xv.z) + fabsf(xv.w);
      }
    }
  }
  int t0 = tg * 2;
  float bb0 = (t0 < 8) ? b1[t0] : b3[t0 - 8];
  float bb1 = (t0 + 1 < 8) ? b1[t0 + 1] : b3[t0 + 1 - 8];
  #pragma unroll
  for (int k2 = 0; k2 < 4; k2++) {
    size_t r = r0 + rg + 32 * k2;
    a[r * 16 + t0]     = fmaxf(acc[k2][0] + bb0, 0.f);
    a[r * 16 + t0 + 1] = fmaxf(acc[k2][1] + bb1, 0.f);
    if (tg == 0) sabs[r] = sa[k2];
  }
}

// ---------- attn BN stats over (B,T) per s ----------
__global__ void k_attnstats(const float* __restrict__ a, float* __restrict__ sstat) {
  int s = blockIdx.x, pool = blockIdx.y;
  float sum = 0.f, sq = 0.f;
  for (int b = threadIdx.x; b < B_; b += blockDim.x) {
    const float* row = &a[((size_t)b * S_ + s) * 16 + pool * 8];
    #pragma unroll
    for (int t = 0; t < 8; t++) { float v = row[t]; sum += v; sq += v * v; }
  }
  __shared__ float rs[2][4];
  int wave = threadIdx.x >> 6, lane = threadIdx.x & 63;
  #pragma unroll
  for (int off = 32; off; off >>= 1) { sum += __shfl_xor(sum, off); sq += __shfl_xor(sq, off); }
  if (lane == 0) { rs[0][wave] = sum; rs[1][wave] = sq; }
  __syncthreads();
  if (threadIdx.x == 0) {
    float S = rs[0][0] + rs[0][1] + rs[0][2] + rs[0][3];
    float Q = rs[1][0] + rs[1][1] + rs[1][2] + rs[1][3];
    float n = (float)(B_ * 8);
    float m = S / n;
    float var = Q / n - m * m;
    sstat[(pool * S_ + s) * 2 + 0] = m;
    sstat[(pool * S_ + s) * 2 + 1] = rsqrtf(var + 1e-5f);
  }
}

// ---------- scores + softmax + weighted pool -> h [B,600] ----------
__global__ __launch_bounds__(256) void k_pool(
    const float* __restrict__ x, const float* __restrict__ a,
    const float* __restrict__ sabs, const float* __restrict__ sstat,
    const float* __restrict__ q1, const float* __restrict__ q2, float* __restrict__ h) {
  int b = blockIdx.x;
  __shared__ float w1s[S_], w2s[S_];
  int tid = threadIdx.x;
  if (tid < S_) {
    float sc1 = 0.f, sc2 = 0.f;
    const float* r1 = &a[((size_t)b * S_ + tid) * 16];
    const float* r2 = r1 + 8;
    float m1 = sstat[(0 * S_ + tid) * 2], rr1 = sstat[(0 * S_ + tid) * 2 + 1];
    float m2 = sstat[(1 * S_ + tid) * 2], rr2 = sstat[(1 * S_ + tid) * 2 + 1];
    #pragma unroll
    for (int t = 0; t < 8; t++) {
      sc1 += (r1[t] - m1) * rr1 * q1[t];
      sc2 += (r2[t] - m2) * rr2 * q2[t];
    }
    if (sabs[(size_t)b * S_ + tid] == 0.f) { sc1 = PADSCORE; sc2 = PADSCORE; }
    w1s[tid] = sc1; w2s[tid] = sc2;
  }
  __syncthreads();
  if (tid < 64) {
    float v1 = (tid < S_) ? w1s[tid] : -3.0e38f;
    float v2 = (tid < S_) ? w2s[tid] : -3.0e38f;
    float m1 = v1, m2 = v2;
    #pragma unroll
    for (int off = 32; off; off >>= 1) {
      m1 = fmaxf(m1, __shfl_xor(m1, off));
      m2 = fmaxf(m2, __shfl_xor(m2, off));
    }
    float e1 = (tid < S_) ? expf(v1 - m1) : 0.f;
    float e2 = (tid < S_) ? expf(v2 - m2) : 0.f;
    float s1 = e1, s2 = e2;
    #pragma unroll
    for (int off = 32; off; off >>= 1) { s1 += __shfl_xor(s1, off); s2 += __shfl_xor(s2, off); }
    if (tid < S_) { w1s[tid] = e1 / s1; w2s[tid] = e2 / s2; }
  }
  __syncthreads();
  for (int e = tid; e < E_; e += 256) {
    float p1 = 0.f, p2 = 0.f;
    for (int s = 0; s < S_; s++) {
      float xv = x[((size_t)b * S_ + s) * E_ + e];
      p1 += xv * w1s[s];
      p2 += xv * w2s[s];
    }
    h[(size_t)b * 600 + e]       = p1;
    h[(size_t)b * 600 + 300 + e] = p2;
  }
}

// ---------- generic fp32 GEMM: Y[M,N] = X[M,K] @ W[N,K]^T (+bias) ----------
__global__ __launch_bounds__(256) void k_gemm_nt(
    const float* __restrict__ X, const float* __restrict__ W, const float* __restrict__ bias,
    float* __restrict__ Y, int M, int N, int K) {
  __shared__ float Xs[16][65];
  __shared__ float Wt[16][65];
  int bm = blockIdx.y * 64, bn = blockIdx.x * 64;
  int tx = threadIdx.x & 15, ty = threadIdx.x >> 4;
  float acc[4][4] = {};
  for (int k0 = 0; k0 < K; k0 += 16) {
    for (int idx = threadIdx.x; idx < 1024; idx += 256) {
      int m = idx >> 4, kk = idx & 15;
      int gk = k0 + kk;
      Xs[kk][m] = (gk < K) ? X[(size_t)(bm + m) * K + gk] : 0.f;
      int gn = bn + m;
      Wt[kk][m] = (gn < N && gk < K) ? W[(size_t)gn * K + gk] : 0.f;
    }
    __syncthreads();
    #pragma unroll
    for (int kk = 0; kk < 16; kk++) {
      float xr[4], wr[4];
      #pragma unroll
      for (int i = 0; i < 4; i++) xr[i] = Xs[kk][ty * 4 + i];
      #pragma unroll
      for (int j = 0; j < 4; j++) wr[j] = Wt[kk][tx * 4 + j];
      #pragma unroll
      for (int i = 0; i < 4; i++)
        #pragma unroll
        for (int j = 0; j < 4; j++) acc[i][j] = fmaf(xr[i], wr[j], acc[i][j]);
    }
    __syncthreads();
  }
  #pragma unroll
  for (int i = 0; i < 4; i++) {
    int gm = bm + ty * 4 + i;
    #pragma unroll
    for (int j = 0; j < 4; j++) {
      int gn = bn + tx * 4 + j;
      if (gn < N) Y[(size_t)gm * N + gn] = acc[i][j] + (bias ? bias[gn] : 0.f);
    }
  }
}

// ---------- column stats (mean/rstd over batch) ----------
__global__ void k_colstat_part(const float* __restrict__ X, float* __restrict__ part,
                               int M, int N) {
  int nblk = gridDim.x;
  int rows = (M + nblk - 1) / nblk;
  int r0 = blockIdx.x * rows, r1 = min(M, r0 + rows);
  for (int c = threadIdx.x; c < N; c += blockDim.x) {
    float s = 0.f, q = 0.f;
    for (int r = r0; r < r1; r++) { float v = X[(size_t)r * N + c]; s += v; q += v * v; }
    part[((size_t)blockIdx.x * N + c) * 2 + 0] = s;
    part[((size_t)blockIdx.x * N + c) * 2 + 1] = q;
  }
}

__global__ void k_colstat_fin(const float* __restrict__ part, float* __restrict__ stat,
                              int N, int nparts, int M) {
  int c = threadIdx.x;
  if (c >= N) return;
  float s = 0.f, q = 0.f;
  for (int p = 0; p < nparts; p++) {
    s += part[((size_t)p * N + c) * 2 + 0];
    q += part[((size_t)p * N + c) * 2 + 1];
  }
  float m = s / (float)M;
  float var = q / (float)M - m * m;
  stat[c * 2 + 0] = m;
  stat[c * 2 + 1] = rsqrtf(var + 1e-5f);
}

// ---------- normalize h5 (writes f32 + padded f16 copy) ----------
__global__ void k_norm_h5(const float* __restrict__ X, const float* __restrict__ stat,
                          float* __restrict__ h5, _Float16* __restrict__ h5h) {
  int idx = blockIdx.x * 256 + threadIdx.x;
  if (idx >= B_ * 320) return;
  int b = idx / 320, c = idx - b * 320;
  if (c < E_) {
    float v = (X[(size_t)b * E_ + c] - stat[c * 2]) * stat[c * 2 + 1];
    h5[(size_t)b * E_ + c] = v;
    h5h[idx] = (_Float16)v;
  } else {
    h5h[idx] = (_Float16)0.f;
  }
}

// ---------- normalize into hcat at column offset ----------
__global__ void k_norm_to(const float* __restrict__ X, const float* __restrict__ stat,
                          float* __restrict__ Y, int off) {
  int idx = blockIdx.x * 256 + threadIdx.x;
  if (idx >= B_ * E_) return;
  int b = idx / E_, c = idx - b * E_;
  Y[(size_t)b * 600 + off + c] = (X[idx] - stat[c * 2]) * stat[c * 2 + 1];
}

// ---------- big MFMA GEMM, barrier-free K-loop ----------
// grid (KSPLIT, 32 mblk); block 256 thr = 4 waves; block tile 64m x 320n (full N).
// Each wave owns all 64 m x its 80 n; its Ws region is private -> no __syncthreads
// in the K-loop (in-order per-wave LDS ops give write->read / read->write safety).
// W tiles register-prefetched one chunk ahead to hide L2 latency.
__global__ __launch_bounds__(256) void k_bigmm3(
    const _Float16* __restrict__ Wg, const _Float16* __restrict__ h5h,
    const int* __restrict__ meta, float* __restrict__ part,
    int nchunks, int cps, int kpad2) {
  __shared__ _Float16 h5L[64][328];    // 41984 B; stride 328 halves == 4 words mod 32
  __shared__ _Float16 Ws[4][80][32];   // 20480 B; per-wave private region
  __shared__ int metaL[200];
  const int ks = blockIdx.x, mblk = blockIdx.y;
  const int tid = threadIdx.x;
  const int wave = tid >> 6, lane = tid & 63, quad = lane >> 4, l16 = lane & 15;
  const int ch0 = ks * cps;
  const int ch1 = min(nchunks, ch0 + cps);

  {
    const _Float16* src = h5h + (size_t)mblk * 64 * 320;
    for (int u = tid; u < 64 * 41; u += 256) {
      int r = u / 41, c8 = u - r * 41;
      h8 v8 = {0, 0, 0, 0, 0, 0, 0, 0};
      if (c8 < 40) v8 = *(const h8*)&src[r * 320 + c8 * 8];
      *(h8*)&h5L[r][c8 * 8] = v8;
    }
    for (int u = tid; u < cps; u += 256)
      metaL[u] = (ch0 + u < nchunks) ? meta[ch0 + u] : 0;
  }
  __syncthreads();   // the only barrier

  f4 acc[4][5];
  #pragma unroll
  for (int i = 0; i < 4; i++)
    #pragma unroll
    for (int j = 0; j < 5; j++) acc[i][j] = (f4){0.f, 0.f, 0.f, 0.f};

  // lane's 5 staging units: u = it*64 + lane -> row n = u>>2 (0..79), seg = u&3
  const _Float16* wgbase = Wg + (size_t)(wave * 80) * kpad2;
  float4 wpre[5];
  const int pn = (lane >> 2), pseg = lane & 3;   // u = it*64+lane -> n = it*16 + pn
  #define ISSUE_W(CH)                                                          \
    _Pragma("unroll")                                                          \
    for (int it = 0; it < 5; it++)                                             \
      wpre[it] = *(const float4*)&wgbase[(size_t)(it * 16 + pn) * kpad2 +      \
                                         (size_t)(CH) * 32 + pseg * 8];
  if (ch0 < ch1) { ISSUE_W(ch0); }

  _Float16 hi[4];
  int iiprev = -1;

  for (int ch = ch0; ch < ch1; ch++) {
    // write prefetched W(ch) into my private Ws region (addr = 4*u words: uniform)
    #pragma unroll
    for (int it = 0; it < 5; it++)
      *(float4*)&Ws[wave][it * 16 + pn][pseg * 8] = wpre[it];
    // prefetch next chunk (overwrites wpre after ds_writes captured operands)
    if (ch + 1 < ch1) { ISSUE_W(ch + 1); }

    const int mt = metaL[ch - ch0];
    const int ii = mt & 0xffff, j0 = mt >> 16;
    if (ii != iiprev) {          // wave-uniform branch; rows run ~9 chunks
      #pragma unroll
      for (int mi = 0; mi < 4; mi++) hi[mi] = h5L[mi * 16 + l16][ii];
      iiprev = ii;
    }
    h8 af[4];
    #pragma unroll
    for (int mi = 0; mi < 4; mi++) {
      h8 vj = *(const h8*)&h5L[mi * 16 + l16][j0 + quad * 8];
      _Float16 h = hi[mi];
      h8 hs = {h, h, h, h, h, h, h, h};
      af[mi] = vj * hs;
    }
    h8 bf[5];
    #pragma unroll
    for (int nt = 0; nt < 5; nt++)
      bf[nt] = *(const h8*)&Ws[wave][nt * 16 + l16][quad * 8];
    #pragma unroll
    for (int mi = 0; mi < 4; mi++)
      #pragma unroll
      for (int nt = 0; nt < 5; nt++)
        acc[mi][nt] = __builtin_amdgcn_mfma_f32_16x16x32_f16(af[mi], bf[nt], acc[mi][nt], 0, 0, 0);
  }

  float* dst = part + (size_t)ks * (B_ * E_);
  #pragma unroll
  for (int mi = 0; mi < 4; mi++) {
    int b = mblk * 64 + mi * 16 + quad * 4;
    #pragma unroll
    for (int nt = 0; nt < 5; nt++) {
      int e = wave * 80 + nt * 16 + l16;
      if (e < E_) {
        #pragma unroll
        for (int r = 0; r < 4; r++)
          dst[(size_t)(b + r) * E_ + e] = acc[mi][nt][r];
      }
    }
  }
  #undef ISSUE_W
}

// ---------- fused split-K reduce + column-stat partials ----------
__global__ __launch_bounds__(256) void k_reduce_stat(
    const float* __restrict__ part, float* __restrict__ h7,
    float* __restrict__ cpart) {
  int blk = blockIdx.x;              // 64 blocks x 32 rows
  int r0 = blk * 32;
  for (int c = threadIdx.x; c < E_; c += 256) {
    float s = 0.f, q = 0.f;
    for (int r = r0; r < r0 + 32; r++) {
      float v = 0.f;
      #pragma unroll
      for (int k2 = 0; k2 < KSPLIT; k2++)
        v += part[(size_t)k2 * (B_ * E_) + (size_t)r * E_ + c];
      h7[(size_t)r * E_ + c] = v;
      s += v; q += v * v;
    }
    cpart[((size_t)blk * E_ + c) * 2 + 0] = s;
    cpart[((size_t)blk * E_ + c) * 2 + 1] = q;
  }
}

extern "C" void kernel_launch(void* const* d_in, const int* in_sizes, int n_in,
                              void* d_out, int out_size, void* d_ws, size_t ws_size,
                              hipStream_t stream) {
  const float* x    = (const float*)d_in[0];
  const float* lemb = (const float*)d_in[1];
  const float* fc1w = (const float*)d_in[2];
  const float* fc1b = (const float*)d_in[3];
  const float* q1   = (const float*)d_in[4];
  const float* fc3w = (const float*)d_in[5];
  const float* fc3b = (const float*)d_in[6];
  const float* q2   = (const float*)d_in[7];
  const float* fc5w = (const float*)d_in[8];
  const float* fc6w = (const float*)d_in[10];
  const float* fc7w = (const float*)d_in[12];
  const float* fc8w = (const float*)d_in[14];
  const float* fc8b = (const float*)d_in[15];
  const float* v    = (const float*)d_in[16];
  float* out = (float*)d_out;
  (void)in_sizes; (void)n_in; (void)out_size; (void)ws_size;

  // chunk enumeration (host-side, deterministic): nchunks = 1586
  int nchunks = 0;
  for (int i = 0; i < 299; i++) { int js = (i + 1) & ~7; nchunks += (300 - js + 31) >> 5; }
  int cps = (nchunks + KSPLIT - 1) / KSPLIT;   // 199
  int kpad2 = nchunks * 32;

  char* base = (char*)d_ws;
  size_t off = 0;
  auto alloc = [&](size_t nbytes) -> char* {
    char* p = base + off;
    off = (off + nbytes + 255) & ~(size_t)255;
    return p;
  };
  int*       meta  = (int*)      alloc((size_t)nchunks * 4);
  _Float16*  Wg    = (_Float16*) alloc((size_t)320 * kpad2 * 2);
  _Float16*  h5h   = (_Float16*) alloc((size_t)B_ * 320 * 2);
  float*     hcat  = (float*)    alloc((size_t)B_ * 600 * 4);
  float*     h7pre = (float*)    alloc((size_t)B_ * E_ * 4);
  float*     out8  = (float*)    alloc((size_t)B_ * E_ * 4);
  float*     cpart = (float*)    alloc((size_t)64 * E_ * 2 * 4);
  float*     cstat = (float*)    alloc((size_t)E_ * 2 * 4);
  size_t part_bytes = (size_t)KSPLIT * B_ * E_ * 4;   // 19.66 MB
  char* scratch = alloc(part_bytes);
  float* a     = (float*)scratch;                     // [R_][16] = 6.55 MB
  float* sabs  = a + (size_t)R_ * 16;
  float* sstat = sabs + R_;
  float* h     = sstat + 256;
  float* h5pre = h + (size_t)B_ * 600;
  float* h5    = h5pre + (size_t)B_ * E_;
  float* h6pre = h5 + (size_t)B_ * E_;
  float* part  = (float*)scratch;                     // reused after phase-1 dead

  // prep
  hipLaunchKernelGGL(k_meta, dim3(1), dim3(320), 0, stream, meta);
  hipLaunchKernelGGL(k_wg2, dim3(nchunks, 20), dim3(256), 0, stream, fc7w, v, meta, Wg, kpad2);
  // attention pools
  hipLaunchKernelGGL(k_attn2, dim3(R_ / 128), dim3(256), 0, stream, x, fc1w, fc1b, fc3w, fc3b, a, sabs);
  hipLaunchKernelGGL(k_attnstats, dim3(S_, 2), dim3(256), 0, stream, a, sstat);
  hipLaunchKernelGGL(k_pool, dim3(B_), dim3(256), 0, stream, x, a, sabs, sstat, q1, q2, h);
  // fc5 + BN -> h5 (f32 + padded f16)
  hipLaunchKernelGGL(k_gemm_nt, dim3(5, 32), dim3(256), 0, stream, h, fc5w, (const float*)nullptr, h5pre, B_, E_, 600);
  hipLaunchKernelGGL(k_colstat_part, dim3(64), dim3(320), 0, stream, h5pre, cpart, B_, E_);
  hipLaunchKernelGGL(k_colstat_fin, dim3(1), dim3(320), 0, stream, cpart, cstat, E_, 64, B_);
  hipLaunchKernelGGL(k_norm_h5, dim3((B_ * 320) / 256), dim3(256), 0, stream, h5pre, cstat, h5, h5h);
  // fc6 + BN -> hcat[:, :300]
  hipLaunchKernelGGL(k_gemm_nt, dim3(5, 32), dim3(256), 0, stream, h5, fc6w, (const float*)nullptr, h6pre, B_, E_, E_);
  hipLaunchKernelGGL(k_colstat_part, dim3(64), dim3(320), 0, stream, h6pre, cpart, B_, E_);
  hipLaunchKernelGGL(k_colstat_fin, dim3(1), dim3(320), 0, stream, cpart, cstat, E_, 64, B_);
  hipLaunchKernelGGL(k_norm_to, dim3((B_ * E_) / 256), dim3(256), 0, stream, h6pre, cstat, hcat, 0);
  // cross-feature GEMM (f16 MFMA, split-K, barrier-free) + BN -> hcat[:, 300:]
  hipLaunchKernelGGL(k_bigmm3, dim3(KSPLIT, 32), dim3(256), 0, stream, Wg, h5h, meta, part, nchunks, cps, kpad2);
  hipLaunchKernelGGL(k_reduce_stat, dim3(64), dim3(256), 0, stream, part, h7pre, cpart);
  hipLaunchKernelGGL(k_colstat_fin, dim3(1), dim3(320), 0, stream, cpart, cstat, E_, 64, B_);
  hipLaunchKernelGGL(k_norm_to, dim3((B_ * E_) / 256), dim3(256), 0, stream, h7pre, cstat, hcat, 300);
  // fc8 + label projection
  hipLaunchKernelGGL(k_gemm_nt, dim3(5, 32), dim3(256), 0, stream, hcat, fc8w, fc8b, out8, B_, E_, 600);
  hipLaunchKernelGGL(k_gemm_nt, dim3(16, 32), dim3(256), 0, stream, out8, lemb, (const float*)nullptr, out, B_, 1000, E_);
}

// Round 4
// 910.659 us; speedup vs baseline: 1.2095x; 1.2095x over previous
//
#include <hip/hip_runtime.h>

#define B_ 2048
#define S_ 50
#define E_ 300
#define NPAIR 44850
#define KSPLIT 8
#define R_ (B_ * S_)            // 102400 rows for attn fc
#define PADSCORE (-4294967295.0f)

typedef _Float16 h8 __attribute__((ext_vector_type(8)));
typedef float f4 __attribute__((ext_vector_type(4)));

// ---------- chunk metadata: each 32-wide k-chunk has a single i, 8-aligned j0 ----------
__global__ void k_meta(int* __restrict__ meta) {
  __shared__ int cnt[304], start[304];
  int i = threadIdx.x;
  if (i < 299) {
    int js = (i + 1) & ~7;
    cnt[i] = (300 - js + 31) >> 5;
  }
  __syncthreads();
  if (threadIdx.x == 0) {
    int s = 0;
    for (int r = 0; r < 299; r++) { start[r] = s; s += cnt[r]; }
  }
  __syncthreads();
  if (i < 299) {
    int js = (i + 1) & ~7;
    for (int c = 0; c < cnt[i]; c++)
      meta[start[i] + c] = i | ((js + 32 * c) << 16);
  }
}

// ---------- Wgf in MFMA B-fragment order ----------
// Wgf[((ch*20 + grp)*64 + lane)*8 + t] = f16( w7[e, p(i,j)] * (v_i . v_j) )
//   where e = grp*16 + (lane&15), k = (lane>>4)*8 + t, j = j0(ch) + k.
// Zeros for invalid (j<=i, j>=300, e>=300) so MFMA pads are inert.
__global__ __launch_bounds__(256) void k_wg3(
    const float* __restrict__ w7, const float* __restrict__ v,
    const int* __restrict__ meta, _Float16* __restrict__ Wgf) {
  __shared__ float gL[32];
  const int ch = blockIdx.x;
  const int mt = meta[ch];
  const int i = mt & 0xffff, j0 = mt >> 16;
  const int t = threadIdx.x;
  if (t < 32) {
    int j = j0 + t;
    float g = 0.f;
    if (j > i && j < 300)
      g = v[i*4+0]*v[j*4+0] + v[i*4+1]*v[j*4+1] + v[i*4+2]*v[j*4+2] + v[i*4+3]*v[j*4+3];
    gL[t] = g;
  }
  __syncthreads();
  const int grp = blockIdx.y * 4 + (t >> 6);
  const int lane = t & 63, l16 = lane & 15, quad = lane >> 4;
  const int e = grp * 16 + l16;
  const int ibase = i * (599 - i) / 2 - i - 1;   // p = ibase + j
  h8 outv;
  #pragma unroll
  for (int tt = 0; tt < 8; tt++) {
    int k = quad * 8 + tt;
    int j = j0 + k;
    float val = 0.f;
    if (j > i && j < 300 && e < 300)
      val = w7[(size_t)e * NPAIR + ibase + j] * gL[k];
    outv[tt] = (_Float16)val;
  }
  *(h8*)&Wgf[(((size_t)ch * 20 + grp) * 64 + lane) * 8] = outv;
}

// ---------- attn fc: a[r][16] = relu(x[r] @ w^T + b), sabs[r] = sum|x[r]| ----------
__global__ __launch_bounds__(256) void k_attn2(
    const float* __restrict__ x, const float* __restrict__ w1, const float* __restrict__ b1,
    const float* __restrict__ w3, const float* __restrict__ b3,
    float* __restrict__ a, float* __restrict__ sabs) {
  __shared__ float xs[128][68];
  __shared__ float wL[16][308];
  const int tid = threadIdx.x;
  const int r0 = blockIdx.x * 128;
  for (int u = tid; u < 16 * 75; u += 256) {
    int t = u / 75, q = u - t * 75;
    float4 v4 = (t < 8) ? *(const float4*)&w1[t * 300 + q * 4]
                        : *(const float4*)&w3[(t - 8) * 300 + q * 4];
    *(float4*)&wL[t][q * 4] = v4;
  }
  const int rg = tid >> 3, tg = tid & 7;
  float acc[4][2] = {};
  float sa[4] = {};
  for (int k0 = 0; k0 < 300; k0 += 64) {
    int w = min(64, 300 - k0);
    __syncthreads();
    #pragma unroll
    for (int it = 0; it < 8; it++) {
      int u = tid + it * 256;
      int r = u >> 4, q = u & 15;
      float4 v4 = {0.f, 0.f, 0.f, 0.f};
      if (q * 4 < w) v4 = *(const float4*)&x[(size_t)(r0 + r) * 300 + k0 + q * 4];
      *(float4*)&xs[r][q * 4] = v4;
    }
    __syncthreads();
    for (int q = 0; q < (w >> 2); q++) {
      float4 w0 = *(float4*)&wL[tg * 2][k0 + q * 4];
      float4 w1v = *(float4*)&wL[tg * 2 + 1][k0 + q * 4];
      #pragma unroll
      for (int k2 = 0; k2 < 4; k2++) {
        float4 xv = *(float4*)&xs[rg + 32 * k2][q * 4];
        acc[k2][0] += xv.x * w0.x + xv.y * w0.y + xv.z * w0.z + xv.w * w0.w;
        acc[k2][1] += xv.x * w1v.x + xv.y * w1v.y + xv.z * w1v.z + xv.w * w1v.w;
        if (tg == 0)
          sa[k2] += fabsf(xv.x) + fabsf(xv.y) + fabsf(xv.z) + fabsf(xv.w);
      }
    }
  }
  int t0 = tg * 2;
  float bb0 = (t0 < 8) ? b1[t0] : b3[t0 - 8];
  float bb1 = (t0 + 1 < 8) ? b1[t0 + 1] : b3[t0 + 1 - 8];
  #pragma unroll
  for (int k2 = 0; k2 < 4; k2++) {
    size_t r = r0 + rg + 32 * k2;
    a[r * 16 + t0]     = fmaxf(acc[k2][0] + bb0, 0.f);
    a[r * 16 + t0 + 1] = fmaxf(acc[k2][1] + bb1, 0.f);
    if (tg == 0) sabs[r] = sa[k2];
  }
}

// ---------- attn BN stats over (B,T) per s ----------
__global__ void k_attnstats(const float* __restrict__ a, float* __restrict__ sstat) {
  int s = blockIdx.x, pool = blockIdx.y;
  float sum = 0.f, sq = 0.f;
  for (int b = threadIdx.x; b < B_; b += blockDim.x) {
    const float* row = &a[((size_t)b * S_ + s) * 16 + pool * 8];
    #pragma unroll
    for (int t = 0; t < 8; t++) { float v = row[t]; sum += v; sq += v * v; }
  }
  __shared__ float rs[2][4];
  int wave = threadIdx.x >> 6, lane = threadIdx.x & 63;
  #pragma unroll
  for (int off = 32; off; off >>= 1) { sum += __shfl_xor(sum, off); sq += __shfl_xor(sq, off); }
  if (lane == 0) { rs[0][wave] = sum; rs[1][wave] = sq; }
  __syncthreads();
  if (threadIdx.x == 0) {
    float S = rs[0][0] + rs[0][1] + rs[0][2] + rs[0][3];
    float Q = rs[1][0] + rs[1][1] + rs[1][2] + rs[1][3];
    float n = (float)(B_ * 8);
    float m = S / n;
    float var = Q / n - m * m;
    sstat[(pool * S_ + s) * 2 + 0] = m;
    sstat[(pool * S_ + s) * 2 + 1] = rsqrtf(var + 1e-5f);
  }
}

// ---------- scores + softmax + weighted pool -> h [B,600] ----------
__global__ __launch_bounds__(256) void k_pool(
    const float* __restrict__ x, const float* __restrict__ a,
    const float* __restrict__ sabs, const float* __restrict__ sstat,
    const float* __restrict__ q1, const float* __restrict__ q2, float* __restrict__ h) {
  int b = blockIdx.x;
  __shared__ float w1s[S_], w2s[S_];
  int tid = threadIdx.x;
  if (tid < S_) {
    float sc1 = 0.f, sc2 = 0.f;
    const float* r1 = &a[((size_t)b * S_ + tid) * 16];
    const float* r2 = r1 + 8;
    float m1 = sstat[(0 * S_ + tid) * 2], rr1 = sstat[(0 * S_ + tid) * 2 + 1];
    float m2 = sstat[(1 * S_ + tid) * 2], rr2 = sstat[(1 * S_ + tid) * 2 + 1];
    #pragma unroll
    for (int t = 0; t < 8; t++) {
      sc1 += (r1[t] - m1) * rr1 * q1[t];
      sc2 += (r2[t] - m2) * rr2 * q2[t];
    }
    if (sabs[(size_t)b * S_ + tid] == 0.f) { sc1 = PADSCORE; sc2 = PADSCORE; }
    w1s[tid] = sc1; w2s[tid] = sc2;
  }
  __syncthreads();
  if (tid < 64) {
    float v1 = (tid < S_) ? w1s[tid] : -3.0e38f;
    float v2 = (tid < S_) ? w2s[tid] : -3.0e38f;
    float m1 = v1, m2 = v2;
    #pragma unroll
    for (int off = 32; off; off >>= 1) {
      m1 = fmaxf(m1, __shfl_xor(m1, off));
      m2 = fmaxf(m2, __shfl_xor(m2, off));
    }
    float e1 = (tid < S_) ? expf(v1 - m1) : 0.f;
    float e2 = (tid < S_) ? expf(v2 - m2) : 0.f;
    float s1 = e1, s2 = e2;
    #pragma unroll
    for (int off = 32; off; off >>= 1) { s1 += __shfl_xor(s1, off); s2 += __shfl_xor(s2, off); }
    if (tid < S_) { w1s[tid] = e1 / s1; w2s[tid] = e2 / s2; }
  }
  __syncthreads();
  for (int e = tid; e < E_; e += 256) {
    float p1 = 0.f, p2 = 0.f;
    for (int s = 0; s < S_; s++) {
      float xv = x[((size_t)b * S_ + s) * E_ + e];
      p1 += xv * w1s[s];
      p2 += xv * w2s[s];
    }
    h[(size_t)b * 600 + e]       = p1;
    h[(size_t)b * 600 + 300 + e] = p2;
  }
}

// ---------- generic fp32 GEMM: Y[M,N] = X[M,K] @ W[N,K]^T (+bias) ----------
__global__ __launch_bounds__(256) void k_gemm_nt(
    const float* __restrict__ X, const float* __restrict__ W, const float* __restrict__ bias,
    float* __restrict__ Y, int M, int N, int K) {
  __shared__ float Xs[16][65];
  __shared__ float Wt[16][65];
  int bm = blockIdx.y * 64, bn = blockIdx.x * 64;
  int tx = threadIdx.x & 15, ty = threadIdx.x >> 4;
  float acc[4][4] = {};
  for (int k0 = 0; k0 < K; k0 += 16) {
    for (int idx = threadIdx.x; idx < 1024; idx += 256) {
      int m = idx >> 4, kk = idx & 15;
      int gk = k0 + kk;
      Xs[kk][m] = (gk < K) ? X[(size_t)(bm + m) * K + gk] : 0.f;
      int gn = bn + m;
      Wt[kk][m] = (gn < N && gk < K) ? W[(size_t)gn * K + gk] : 0.f;
    }
    __syncthreads();
    #pragma unroll
    for (int kk = 0; kk < 16; kk++) {
      float xr[4], wr[4];
      #pragma unroll
      for (int i = 0; i < 4; i++) xr[i] = Xs[kk][ty * 4 + i];
      #pragma unroll
      for (int j = 0; j < 4; j++) wr[j] = Wt[kk][tx * 4 + j];
      #pragma unroll
      for (int i = 0; i < 4; i++)
        #pragma unroll
        for (int j = 0; j < 4; j++) acc[i][j] = fmaf(xr[i], wr[j], acc[i][j]);
    }
    __syncthreads();
  }
  #pragma unroll
  for (int i = 0; i < 4; i++) {
    int gm = bm + ty * 4 + i;
    #pragma unroll
    for (int j = 0; j < 4; j++) {
      int gn = bn + tx * 4 + j;
      if (gn < N) Y[(size_t)gm * N + gn] = acc[i][j] + (bias ? bias[gn] : 0.f);
    }
  }
}

// ---------- column stats (mean/rstd over batch) ----------
__global__ void k_colstat_part(const float* __restrict__ X, float* __restrict__ part,
                               int M, int N) {
  int nblk = gridDim.x;
  int rows = (M + nblk - 1) / nblk;
  int r0 = blockIdx.x * rows, r1 = min(M, r0 + rows);
  for (int c = threadIdx.x; c < N; c += blockDim.x) {
    float s = 0.f, q = 0.f;
    for (int r = r0; r < r1; r++) { float v = X[(size_t)r * N + c]; s += v; q += v * v; }
    part[((size_t)blockIdx.x * N + c) * 2 + 0] = s;
    part[((size_t)blockIdx.x * N + c) * 2 + 1] = q;
  }
}

__global__ void k_colstat_fin(const float* __restrict__ part, float* __restrict__ stat,
                              int N, int nparts, int M) {
  int c = threadIdx.x;
  if (c >= N) return;
  float s = 0.f, q = 0.f;
  for (int p = 0; p < nparts; p++) {
    s += part[((size_t)p * N + c) * 2 + 0];
    q += part[((size_t)p * N + c) * 2 + 1];
  }
  float m = s / (float)M;
  float var = q / (float)M - m * m;
  stat[c * 2 + 0] = m;
  stat[c * 2 + 1] = rsqrtf(var + 1e-5f);
}

// ---------- normalize h5 (writes f32 + padded f16 copy) ----------
__global__ void k_norm_h5(const float* __restrict__ X, const float* __restrict__ stat,
                          float* __restrict__ h5, _Float16* __restrict__ h5h) {
  int idx = blockIdx.x * 256 + threadIdx.x;
  if (idx >= B_ * 320) return;
  int b = idx / 320, c = idx - b * 320;
  if (c < E_) {
    float v = (X[(size_t)b * E_ + c] - stat[c * 2]) * stat[c * 2 + 1];
    h5[(size_t)b * E_ + c] = v;
    h5h[idx] = (_Float16)v;
  } else {
    h5h[idx] = (_Float16)0.f;
  }
}

// ---------- normalize into hcat at column offset ----------
__global__ void k_norm_to(const float* __restrict__ X, const float* __restrict__ stat,
                          float* __restrict__ Y, int off) {
  int idx = blockIdx.x * 256 + threadIdx.x;
  if (idx >= B_ * E_) return;
  int b = idx / E_, c = idx - b * E_;
  Y[(size_t)b * 600 + off + c] = (X[idx] - stat[c * 2]) * stat[c * 2 + 1];
}

// ---------- big MFMA GEMM v4: B-fragments straight from global, LDS = h5 only ----------
// grid (8 ks, 32 mblk, 2 nblk) = 512 blocks; block 256 thr = 4 waves (2 wm x 2 wn).
// Wave owns 32m x 80n. No barriers in K-loop; B prefetched 2 chunks ahead.
__global__ __launch_bounds__(256, 3) void k_bigmm4(
    const _Float16* __restrict__ Wgf, const _Float16* __restrict__ h5h,
    const int* __restrict__ meta, float* __restrict__ part,
    int nchunks, int cps) {
  __shared__ _Float16 h5L[64][328];    // 41984 B; cols 300..327 zeroed (j-pad reads)
  __shared__ int metaL[200];
  const int ks = blockIdx.x, mblk = blockIdx.y, nblk = blockIdx.z;
  const int tid = threadIdx.x;
  const int wave = tid >> 6, lane = tid & 63, quad = lane >> 4, l16 = lane & 15;
  const int wm = wave >> 1, wn = wave & 1;
  const int ch0 = ks * cps;
  const int ch1 = min(nchunks, ch0 + cps);

  {
    const _Float16* src = h5h + (size_t)mblk * 64 * 320;
    for (int u = tid; u < 64 * 41; u += 256) {
      int r = u / 41, c8 = u - r * 41;
      h8 v8 = {0, 0, 0, 0, 0, 0, 0, 0};
      if (c8 < 40) v8 = *(const h8*)&src[r * 320 + c8 * 8];
      *(h8*)&h5L[r][c8 * 8] = v8;
    }
    for (int u = tid; u < 200; u += 256)
      metaL[u] = (u < cps && ch0 + u < nchunks) ? meta[ch0 + u] : 0;
  }
  __syncthreads();   // only barrier

  f4 acc[2][5];
  #pragma unroll
  for (int i = 0; i < 2; i++)
    #pragma unroll
    for (int j = 0; j < 5; j++) acc[i][j] = (f4){0.f, 0.f, 0.f, 0.f};

  // B-frag base: grp = nblk*10 + wn*5 + nt; addr = ((ch*20+grp)*64+lane)*8 halves
  const _Float16* wbase = Wgf + ((size_t)(nblk * 10 + wn * 5) * 64 + lane) * 8;
  h8 bA[5], bB[5];
  #define LOADB(DST, CH)                                                       \
    _Pragma("unroll")                                                          \
    for (int nt = 0; nt < 5; nt++)                                             \
      DST[nt] = *(const h8*)&wbase[(size_t)(CH) * 10240 + nt * 512];

  if (ch0 < ch1) { LOADB(bA, ch0); }
  if (ch0 + 1 < ch1) { LOADB(bB, ch0 + 1); }

  _Float16 hi[2];
  int iiprev = -1;

  auto step = [&](int ch, h8* bf) {
    const int mt = metaL[ch - ch0];
    const int ii = mt & 0xffff, j0 = mt >> 16;
    if (ii != iiprev) {                 // wave-uniform; rows run ~8-9 chunks
      #pragma unroll
      for (int mi = 0; mi < 2; mi++) hi[mi] = h5L[wm * 32 + mi * 16 + l16][ii];
      iiprev = ii;
    }
    h8 af[2];
    #pragma unroll
    for (int mi = 0; mi < 2; mi++) {
      h8 vj = *(const h8*)&h5L[wm * 32 + mi * 16 + l16][j0 + quad * 8];
      _Float16 h = hi[mi];
      h8 hs = {h, h, h, h, h, h, h, h};
      af[mi] = vj * hs;
    }
    #pragma unroll
    for (int mi = 0; mi < 2; mi++)
      #pragma unroll
      for (int nt = 0; nt < 5; nt++)
        acc[mi][nt] = __builtin_amdgcn_mfma_f32_16x16x32_f16(af[mi], bf[nt], acc[mi][nt], 0, 0, 0);
  };

  int ch = ch0;
  while (ch < ch1) {
    step(ch, bA);
    if (ch + 2 < ch1) { LOADB(bA, ch + 2); }
    ch++;
    if (ch < ch1) {
      step(ch, bB);
      if (ch + 2 < ch1) { LOADB(bB, ch + 2); }
      ch++;
    }
  }
  #undef LOADB

  float* dst = part + (size_t)ks * (B_ * E_);
  #pragma unroll
  for (int mi = 0; mi < 2; mi++) {
    int b = mblk * 64 + wm * 32 + mi * 16 + quad * 4;
    #pragma unroll
    for (int nt = 0; nt < 5; nt++) {
      int e = nblk * 160 + wn * 80 + nt * 16 + l16;
      if (e < E_) {
        #pragma unroll
        for (int r = 0; r < 4; r++)
          dst[(size_t)(b + r) * E_ + e] = acc[mi][nt][r];
      }
    }
  }
}

// ---------- fused split-K reduce + column-stat partials ----------
__global__ __launch_bounds__(256) void k_reduce_stat(
    const float* __restrict__ part, float* __restrict__ h7,
    float* __restrict__ cpart) {
  int blk = blockIdx.x;              // 64 blocks x 32 rows
  int r0 = blk * 32;
  for (int c = threadIdx.x; c < E_; c += 256) {
    float s = 0.f, q = 0.f;
    for (int r = r0; r < r0 + 32; r++) {
      float v = 0.f;
      #pragma unroll
      for (int k2 = 0; k2 < KSPLIT; k2++)
        v += part[(size_t)k2 * (B_ * E_) + (size_t)r * E_ + c];
      h7[(size_t)r * E_ + c] = v;
      s += v; q += v * v;
    }
    cpart[((size_t)blk * E_ + c) * 2 + 0] = s;
    cpart[((size_t)blk * E_ + c) * 2 + 1] = q;
  }
}

extern "C" void kernel_launch(void* const* d_in, const int* in_sizes, int n_in,
                              void* d_out, int out_size, void* d_ws, size_t ws_size,
                              hipStream_t stream) {
  const float* x    = (const float*)d_in[0];
  const float* lemb = (const float*)d_in[1];
  const float* fc1w = (const float*)d_in[2];
  const float* fc1b = (const float*)d_in[3];
  const float* q1   = (const float*)d_in[4];
  const float* fc3w = (const float*)d_in[5];
  const float* fc3b = (const float*)d_in[6];
  const float* q2   = (const float*)d_in[7];
  const float* fc5w = (const float*)d_in[8];
  const float* fc6w = (const float*)d_in[10];
  const float* fc7w = (const float*)d_in[12];
  const float* fc8w = (const float*)d_in[14];
  const float* fc8b = (const float*)d_in[15];
  const float* v    = (const float*)d_in[16];
  float* out = (float*)d_out;
  (void)in_sizes; (void)n_in; (void)out_size; (void)ws_size;

  // chunk enumeration (host-side, deterministic): nchunks = 1586
  int nchunks = 0;
  for (int i = 0; i < 299; i++) { int js = (i + 1) & ~7; nchunks += (300 - js + 31) >> 5; }
  int cps = (nchunks + KSPLIT - 1) / KSPLIT;   // 199

  char* base = (char*)d_ws;
  size_t off = 0;
  auto alloc = [&](size_t nbytes) -> char* {
    char* p = base + off;
    off = (off + nbytes + 255) & ~(size_t)255;
    return p;
  };
  int*       meta  = (int*)      alloc((size_t)nchunks * 4);
  _Float16*  Wgf   = (_Float16*) alloc((size_t)nchunks * 20 * 64 * 8 * 2);  // 32.5 MB
  _Float16*  h5h   = (_Float16*) alloc((size_t)B_ * 320 * 2);
  float*     hcat  = (float*)    alloc((size_t)B_ * 600 * 4);
  float*     h7pre = (float*)    alloc((size_t)B_ * E_ * 4);
  float*     out8  = (float*)    alloc((size_t)B_ * E_ * 4);
  float*     cpart = (float*)    alloc((size_t)64 * E_ * 2 * 4);
  float*     cstat = (float*)    alloc((size_t)E_ * 2 * 4);
  size_t part_bytes = (size_t)KSPLIT * B_ * E_ * 4;   // 19.66 MB
  char* scratch = alloc(part_bytes);
  float* a     = (float*)scratch;                     // [R_][16] = 6.55 MB
  float* sabs  = a + (size_t)R_ * 16;
  float* sstat = sabs + R_;
  float* h     = sstat + 256;
  float* h5pre = h + (size_t)B_ * 600;
  float* h5    = h5pre + (size_t)B_ * E_;
  float* h6pre = h5 + (size_t)B_ * E_;
  float* part  = (float*)scratch;                     // reused after phase-1 dead

  // prep
  hipLaunchKernelGGL(k_meta, dim3(1), dim3(320), 0, stream, meta);
  hipLaunchKernelGGL(k_wg3, dim3(nchunks, 5), dim3(256), 0, stream, fc7w, v, meta, Wgf);
  // attention pools
  hipLaunchKernelGGL(k_attn2, dim3(R_ / 128), dim3(256), 0, stream, x, fc1w, fc1b, fc3w, fc3b, a, sabs);
  hipLaunchKernelGGL(k_attnstats, dim3(S_, 2), dim3(256), 0, stream, a, sstat);
  hipLaunchKernelGGL(k_pool, dim3(B_), dim3(256), 0, stream, x, a, sabs, sstat, q1, q2, h);
  // fc5 + BN -> h5 (f32 + padded f16)
  hipLaunchKernelGGL(k_gemm_nt, dim3(5, 32), dim3(256), 0, stream, h, fc5w, (const float*)nullptr, h5pre, B_, E_, 600);
  hipLaunchKernelGGL(k_colstat_part, dim3(64), dim3(320), 0, stream, h5pre, cpart, B_, E_);
  hipLaunchKernelGGL(k_colstat_fin, dim3(1), dim3(320), 0, stream, cpart, cstat, E_, 64, B_);
  hipLaunchKernelGGL(k_norm_h5, dim3((B_ * 320) / 256), dim3(256), 0, stream, h5pre, cstat, h5, h5h);
  // fc6 + BN -> hcat[:, :300]
  hipLaunchKernelGGL(k_gemm_nt, dim3(5, 32), dim3(256), 0, stream, h5, fc6w, (const float*)nullptr, h6pre, B_, E_, E_);
  hipLaunchKernelGGL(k_colstat_part, dim3(64), dim3(320), 0, stream, h6pre, cpart, B_, E_);
  hipLaunchKernelGGL(k_colstat_fin, dim3(1), dim3(320), 0, stream, cpart, cstat, E_, 64, B_);
  hipLaunchKernelGGL(k_norm_to, dim3((B_ * E_) / 256), dim3(256), 0, stream, h6pre, cstat, hcat, 0);
  // cross-feature GEMM (f16 MFMA, split-K, B-from-global) + BN -> hcat[:, 300:]
  hipLaunchKernelGGL(k_bigmm4, dim3(KSPLIT, 32, 2), dim3(256), 0, stream, Wgf, h5h, meta, part, nchunks, cps);
  hipLaunchKernelGGL(k_reduce_stat, dim3(64), dim3(256), 0, stream, part, h7pre, cpart);
  hipLaunchKernelGGL(k_colstat_fin, dim3(1), dim3(320), 0, stream, cpart, cstat, E_, 64, B_);
  hipLaunchKernelGGL(k_norm_to, dim3((B_ * E_) / 256), dim3(256), 0, stream, h7pre, cstat, hcat, 300);
  // fc8 + label projection
  hipLaunchKernelGGL(k_gemm_nt, dim3(5, 32), dim3(256), 0, stream, hcat, fc8w, fc8b, out8, B_, E_, 600);
  hipLaunchKernelGGL(k_gemm_nt, dim3(16, 32), dim3(256), 0, stream, out8, lemb, (const float*)nullptr, out, B_, 1000, E_);
}

// Round 5
// 738.413 us; speedup vs baseline: 1.4916x; 1.2333x over previous
//
#include <hip/hip_runtime.h>

#define B_ 2048
#define S_ 50
#define E_ 300
#define NPAIR 44850
#define KSPLIT 8
#define R_ (B_ * S_)            // 102400 rows for attn fc
#define PADSCORE (-4294967295.0f)

typedef _Float16 h8 __attribute__((ext_vector_type(8)));
typedef float f4 __attribute__((ext_vector_type(4)));

// ---------- chunk metadata: each 32-wide k-chunk has a single i, 8-aligned j0 ----------
__global__ void k_meta(int* __restrict__ meta) {
  __shared__ int cnt[304], start[304];
  int i = threadIdx.x;
  if (i < 299) {
    int js = (i + 1) & ~7;
    cnt[i] = (300 - js + 31) >> 5;
  }
  __syncthreads();
  if (threadIdx.x == 0) {
    int s = 0;
    for (int r = 0; r < 299; r++) { start[r] = s; s += cnt[r]; }
  }
  __syncthreads();
  if (i < 299) {
    int js = (i + 1) & ~7;
    for (int c = 0; c < cnt[i]; c++)
      meta[start[i] + c] = i | ((js + 32 * c) << 16);
  }
}

// ---------- Wgf in MFMA B-fragment order (cross-feature weights * g) ----------
__global__ __launch_bounds__(256) void k_wg3(
    const float* __restrict__ w7, const float* __restrict__ v,
    const int* __restrict__ meta, _Float16* __restrict__ Wgf) {
  __shared__ float gL[32];
  const int ch = blockIdx.x;
  const int mt = meta[ch];
  const int i = mt & 0xffff, j0 = mt >> 16;
  const int t = threadIdx.x;
  if (t < 32) {
    int j = j0 + t;
    float g = 0.f;
    if (j > i && j < 300)
      g = v[i*4+0]*v[j*4+0] + v[i*4+1]*v[j*4+1] + v[i*4+2]*v[j*4+2] + v[i*4+3]*v[j*4+3];
    gL[t] = g;
  }
  __syncthreads();
  const int grp = blockIdx.y * 4 + (t >> 6);
  const int lane = t & 63, l16 = lane & 15, quad = lane >> 4;
  const int e = grp * 16 + l16;
  const int ibase = i * (599 - i) / 2 - i - 1;   // p = ibase + j
  h8 outv;
  #pragma unroll
  for (int tt = 0; tt < 8; tt++) {
    int k = quad * 8 + tt;
    int j = j0 + k;
    float val = 0.f;
    if (j > i && j < 300 && e < 300)
      val = w7[(size_t)e * NPAIR + ibase + j] * gL[k];
    outv[tt] = (_Float16)val;
  }
  *(h8*)&Wgf[(((size_t)ch * 20 + grp) * 64 + lane) * 8] = outv;
}

// ---------- generic weight -> MFMA B-fragment order converter ----------
// Wf[((kt*ngrp + grp)*64 + lane)*8 + t] = f16(w[e][k]), e=grp*16+(lane&15),
// k = kt*32 + (lane>>4)*8 + t; zeros outside [N,K).
__global__ __launch_bounds__(256) void k_wf(
    const float* __restrict__ w, _Float16* __restrict__ Wf,
    int N, int K, int ngrp) {
  const int kt = blockIdx.x;
  const int grp = blockIdx.y * 4 + (threadIdx.x >> 6);
  const int lane = threadIdx.x & 63, l16 = lane & 15, quad = lane >> 4;
  const int e = grp * 16 + l16;
  if (grp >= ngrp) return;
  h8 o;
  #pragma unroll
  for (int tt = 0; tt < 8; tt++) {
    int k = kt * 32 + quad * 8 + tt;
    float val = (e < N && k < K) ? w[(size_t)e * K + k] : 0.f;
    o[tt] = (_Float16)val;
  }
  *(h8*)&Wf[(((size_t)kt * ngrp + grp) * 64 + lane) * 8] = o;
}

// ---------- attn fc: a[r][16] = relu(x[r] @ w^T + b), sabs[r] = sum|x[r]| ----------
__global__ __launch_bounds__(256) void k_attn2(
    const float* __restrict__ x, const float* __restrict__ w1, const float* __restrict__ b1,
    const float* __restrict__ w3, const float* __restrict__ b3,
    float* __restrict__ a, float* __restrict__ sabs) {
  __shared__ float xs[128][68];
  __shared__ float wL[16][308];
  const int tid = threadIdx.x;
  const int r0 = blockIdx.x * 128;
  for (int u = tid; u < 16 * 75; u += 256) {
    int t = u / 75, q = u - t * 75;
    float4 v4 = (t < 8) ? *(const float4*)&w1[t * 300 + q * 4]
                        : *(const float4*)&w3[(t - 8) * 300 + q * 4];
    *(float4*)&wL[t][q * 4] = v4;
  }
  const int rg = tid >> 3, tg = tid & 7;
  float acc[4][2] = {};
  float sa[4] = {};
  for (int k0 = 0; k0 < 300; k0 += 64) {
    int w = min(64, 300 - k0);
    __syncthreads();
    #pragma unroll
    for (int it = 0; it < 8; it++) {
      int u = tid + it * 256;
      int r = u >> 4, q = u & 15;
      float4 v4 = {0.f, 0.f, 0.f, 0.f};
      if (q * 4 < w) v4 = *(const float4*)&x[(size_t)(r0 + r) * 300 + k0 + q * 4];
      *(float4*)&xs[r][q * 4] = v4;
    }
    __syncthreads();
    for (int q = 0; q < (w >> 2); q++) {
      float4 w0 = *(float4*)&wL[tg * 2][k0 + q * 4];
      float4 w1v = *(float4*)&wL[tg * 2 + 1][k0 + q * 4];
      #pragma unroll
      for (int k2 = 0; k2 < 4; k2++) {
        float4 xv = *(float4*)&xs[rg + 32 * k2][q * 4];
        acc[k2][0] += xv.x * w0.x + xv.y * w0.y + xv.z * w0.z + xv.w * w0.w;
        acc[k2][1] += xv.x * w1v.x + xv.y * w1v.y + xv.z * w1v.z + xv.w * w1v.w;
        if (tg == 0)
          sa[k2] += fabsf(xv.x) + fabsf(xv.y) + fabsf(xv.z) + fabsf(xv.w);
      }
    }
  }
  int t0 = tg * 2;
  float bb0 = (t0 < 8) ? b1[t0] : b3[t0 - 8];
  float bb1 = (t0 + 1 < 8) ? b1[t0 + 1] : b3[t0 + 1 - 8];
  #pragma unroll
  for (int k2 = 0; k2 < 4; k2++) {
    size_t r = r0 + rg + 32 * k2;
    a[r * 16 + t0]     = fmaxf(acc[k2][0] + bb0, 0.f);
    a[r * 16 + t0 + 1] = fmaxf(acc[k2][1] + bb1, 0.f);
    if (tg == 0) sabs[r] = sa[k2];
  }
}

// ---------- attn BN stats over (B,T) per s ----------
__global__ void k_attnstats(const float* __restrict__ a, float* __restrict__ sstat) {
  int s = blockIdx.x, pool = blockIdx.y;
  float sum = 0.f, sq = 0.f;
  for (int b = threadIdx.x; b < B_; b += blockDim.x) {
    const float* row = &a[((size_t)b * S_ + s) * 16 + pool * 8];
    #pragma unroll
    for (int t = 0; t < 8; t++) { float v = row[t]; sum += v; sq += v * v; }
  }
  __shared__ float rs[2][4];
  int wave = threadIdx.x >> 6, lane = threadIdx.x & 63;
  #pragma unroll
  for (int off = 32; off; off >>= 1) { sum += __shfl_xor(sum, off); sq += __shfl_xor(sq, off); }
  if (lane == 0) { rs[0][wave] = sum; rs[1][wave] = sq; }
  __syncthreads();
  if (threadIdx.x == 0) {
    float S = rs[0][0] + rs[0][1] + rs[0][2] + rs[0][3];
    float Q = rs[1][0] + rs[1][1] + rs[1][2] + rs[1][3];
    float n = (float)(B_ * 8);
    float m = S / n;
    float var = Q / n - m * m;
    sstat[(pool * S_ + s) * 2 + 0] = m;
    sstat[(pool * S_ + s) * 2 + 1] = rsqrtf(var + 1e-5f);
  }
}

// ---------- scores + softmax + weighted pool -> hh f16 [B][608] (zero-padded) ----------
__global__ __launch_bounds__(256) void k_pool(
    const float* __restrict__ x, const float* __restrict__ a,
    const float* __restrict__ sabs, const float* __restrict__ sstat,
    const float* __restrict__ q1, const float* __restrict__ q2,
    _Float16* __restrict__ hh) {
  int b = blockIdx.x;
  __shared__ float w1s[S_], w2s[S_];
  int tid = threadIdx.x;
  if (tid < S_) {
    float sc1 = 0.f, sc2 = 0.f;
    const float* r1 = &a[((size_t)b * S_ + tid) * 16];
    const float* r2 = r1 + 8;
    float m1 = sstat[(0 * S_ + tid) * 2], rr1 = sstat[(0 * S_ + tid) * 2 + 1];
    float m2 = sstat[(1 * S_ + tid) * 2], rr2 = sstat[(1 * S_ + tid) * 2 + 1];
    #pragma unroll
    for (int t = 0; t < 8; t++) {
      sc1 += (r1[t] - m1) * rr1 * q1[t];
      sc2 += (r2[t] - m2) * rr2 * q2[t];
    }
    if (sabs[(size_t)b * S_ + tid] == 0.f) { sc1 = PADSCORE; sc2 = PADSCORE; }
    w1s[tid] = sc1; w2s[tid] = sc2;
  }
  __syncthreads();
  if (tid < 64) {
    float v1 = (tid < S_) ? w1s[tid] : -3.0e38f;
    float v2 = (tid < S_) ? w2s[tid] : -3.0e38f;
    float m1 = v1, m2 = v2;
    #pragma unroll
    for (int off = 32; off; off >>= 1) {
      m1 = fmaxf(m1, __shfl_xor(m1, off));
      m2 = fmaxf(m2, __shfl_xor(m2, off));
    }
    float e1 = (tid < S_) ? expf(v1 - m1) : 0.f;
    float e2 = (tid < S_) ? expf(v2 - m2) : 0.f;
    float s1 = e1, s2 = e2;
    #pragma unroll
    for (int off = 32; off; off >>= 1) { s1 += __shfl_xor(s1, off); s2 += __shfl_xor(s2, off); }
    if (tid < S_) { w1s[tid] = e1 / s1; w2s[tid] = e2 / s2; }
  }
  __syncthreads();
  for (int e = tid; e < E_; e += 256) {
    float p1 = 0.f, p2 = 0.f;
    for (int s = 0; s < S_; s++) {
      float xv = x[((size_t)b * S_ + s) * E_ + e];
      p1 += xv * w1s[s];
      p2 += xv * w2s[s];
    }
    hh[(size_t)b * 608 + e]       = (_Float16)p1;
    hh[(size_t)b * 608 + 300 + e] = (_Float16)p2;
  }
  if (tid < 8) hh[(size_t)b * 608 + 600 + tid] = (_Float16)0.f;
}

// ---------- f16 MFMA GEMM: Y = Xh @ Wf^T (frag-ordered W), fp32 out/partials ----------
// grid (M/64 mblk, nblkN, ksplit); block 256 = 4 waves (wm,wn 2x2); wave 32m x 80n.
// X staged once into LDS (<=320 cols per ks); B-frags direct from global; no K barriers.
__global__ __launch_bounds__(256) void k_gemmf(
    const _Float16* __restrict__ Xh, int ldx,
    const _Float16* __restrict__ Wf, int ngrp,
    float* __restrict__ dst, int N,
    int nchunk, int cps) {
  __shared__ _Float16 XL[64][328];
  const int mblk = blockIdx.x, nblk = blockIdx.y, ks = blockIdx.z;
  const int tid = threadIdx.x;
  const int wave = tid >> 6, lane = tid & 63, quad = lane >> 4, l16 = lane & 15;
  const int wm = wave >> 1, wn = wave & 1;
  const int ck0 = ks * cps, ck1 = min(nchunk, ck0 + cps);
  const int ncol8 = (ck1 - ck0) * 4;
  {
    const _Float16* src = Xh + (size_t)mblk * 64 * ldx + ck0 * 32;
    for (int u = tid; u < 64 * ncol8; u += 256) {
      int r = u / ncol8, c8 = u - r * ncol8;
      *(h8*)&XL[r][c8 * 8] = *(const h8*)&src[(size_t)r * ldx + c8 * 8];
    }
  }
  __syncthreads();

  f4 acc[2][5];
  #pragma unroll
  for (int i = 0; i < 2; i++)
    #pragma unroll
    for (int j = 0; j < 5; j++) acc[i][j] = (f4){0.f, 0.f, 0.f, 0.f};

  const int gbase = nblk * 10 + wn * 5;
  const _Float16* wb = Wf + ((size_t)gbase * 64 + lane) * 8;
  h8 bA[5], bB[5];
  #define LOADB(DST, CH)                                                        \
    _Pragma("unroll")                                                           \
    for (int nt = 0; nt < 5; nt++)                                              \
      DST[nt] = (gbase + nt < ngrp)                                             \
          ? *(const h8*)&wb[((size_t)(CH) * ngrp + nt) * 512]                   \
          : (h8){0, 0, 0, 0, 0, 0, 0, 0};

  if (ck0 < ck1) { LOADB(bA, ck0); }
  if (ck0 + 1 < ck1) { LOADB(bB, ck0 + 1); }

  auto step = [&](int ch, h8* bf) {
    int c0 = (ch - ck0) * 32 + quad * 8;
    h8 af[2];
    #pragma unroll
    for (int mi = 0; mi < 2; mi++)
      af[mi] = *(const h8*)&XL[wm * 32 + mi * 16 + l16][c0];
    #pragma unroll
    for (int mi = 0; mi < 2; mi++)
      #pragma unroll
      for (int nt = 0; nt < 5; nt++)
        acc[mi][nt] = __builtin_amdgcn_mfma_f32_16x16x32_f16(af[mi], bf[nt], acc[mi][nt], 0, 0, 0);
  };

  int ch = ck0;
  while (ch < ck1) {
    step(ch, bA);
    if (ch + 2 < ck1) { LOADB(bA, ch + 2); }
    ch++;
    if (ch < ck1) {
      step(ch, bB);
      if (ch + 2 < ck1) { LOADB(bB, ch + 2); }
      ch++;
    }
  }
  #undef LOADB

  float* d = dst + (size_t)ks * ((size_t)B_ * N);
  #pragma unroll
  for (int mi = 0; mi < 2; mi++) {
    int b = mblk * 64 + wm * 32 + mi * 16 + quad * 4;
    #pragma unroll
    for (int nt = 0; nt < 5; nt++) {
      int e = (gbase + nt) * 16 + l16;
      if (e < N) {
        #pragma unroll
        for (int r = 0; r < 4; r++)
          d[(size_t)(b + r) * N + e] = acc[mi][nt][r];
      }
    }
  }
}

// ---------- fused split-K reduce + column-stat partials ----------
__global__ __launch_bounds__(256) void k_reduce_stat(
    const float* __restrict__ part, float* __restrict__ pre,
    float* __restrict__ cpart, int ksp) {
  int blk = blockIdx.x;              // 64 blocks x 32 rows
  int r0 = blk * 32;
  for (int c = threadIdx.x; c < E_; c += 256) {
    float s = 0.f, q = 0.f;
    for (int r = r0; r < r0 + 32; r++) {
      float v = 0.f;
      for (int k2 = 0; k2 < ksp; k2++)
        v += part[(size_t)k2 * (B_ * E_) + (size_t)r * E_ + c];
      pre[(size_t)r * E_ + c] = v;
      s += v; q += v * v;
    }
    cpart[((size_t)blk * E_ + c) * 2 + 0] = s;
    cpart[((size_t)blk * E_ + c) * 2 + 1] = q;
  }
}

__global__ void k_colstat_fin(const float* __restrict__ part, float* __restrict__ stat,
                              int N, int nparts, int M) {
  int c = threadIdx.x;
  if (c >= N) return;
  float s = 0.f, q = 0.f;
  for (int p = 0; p < nparts; p++) {
    s += part[((size_t)p * N + c) * 2 + 0];
    q += part[((size_t)p * N + c) * 2 + 1];
  }
  float m = s / (float)M;
  float var = q / (float)M - m * m;
  stat[c * 2 + 0] = m;
  stat[c * 2 + 1] = rsqrtf(var + 1e-5f);
}

// ---------- normalize -> h5h f16 [B][320] (zero-padded) ----------
__global__ void k_norm_h5h(const float* __restrict__ X, const float* __restrict__ stat,
                           _Float16* __restrict__ h5h) {
  int idx = blockIdx.x * 256 + threadIdx.x;
  if (idx >= B_ * 320) return;
  int b = idx / 320, c = idx - b * 320;
  if (c < E_) {
    float v = (X[(size_t)b * E_ + c] - stat[c * 2]) * stat[c * 2 + 1];
    h5h[idx] = (_Float16)v;
  } else {
    h5h[idx] = (_Float16)0.f;
  }
}

// ---------- normalize -> hcath f16 [B][608] at column offset (pad on off=300 pass) ----------
__global__ void k_norm_hcat(const float* __restrict__ X, const float* __restrict__ stat,
                            _Float16* __restrict__ Y, int off, int pad) {
  int W = 300 + pad;
  int idx = blockIdx.x * 256 + threadIdx.x;
  if (idx >= B_ * W) return;
  int b = idx / W, c = idx - b * W;
  if (c < 300) {
    float v = (X[(size_t)b * E_ + c] - stat[c * 2]) * stat[c * 2 + 1];
    Y[(size_t)b * 608 + off + c] = (_Float16)v;
  } else {
    Y[(size_t)b * 608 + 600 + (c - 300)] = (_Float16)0.f;
  }
}

// ---------- fc8 epilogue: reduce 4 partials + bias -> out8h f16 [B][320] ----------
__global__ void k_redbias_h(const float* __restrict__ part, const float* __restrict__ bias,
                            _Float16* __restrict__ out8h) {
  int idx = blockIdx.x * 256 + threadIdx.x;
  if (idx >= B_ * 320) return;
  int b = idx / 320, c = idx - b * 320;
  if (c < E_) {
    float s = bias[c];
    #pragma unroll
    for (int k2 = 0; k2 < 4; k2++)
      s += part[(size_t)k2 * (B_ * E_) + (size_t)b * E_ + c];
    out8h[idx] = (_Float16)s;
  } else {
    out8h[idx] = (_Float16)0.f;
  }
}

// ---------- big MFMA GEMM v4 (unchanged, proven) ----------
__global__ __launch_bounds__(256, 3) void k_bigmm4(
    const _Float16* __restrict__ Wgf, const _Float16* __restrict__ h5h,
    const int* __restrict__ meta, float* __restrict__ part,
    int nchunks, int cps) {
  __shared__ _Float16 h5L[64][328];
  __shared__ int metaL[200];
  const int ks = blockIdx.x, mblk = blockIdx.y, nblk = blockIdx.z;
  const int tid = threadIdx.x;
  const int wave = tid >> 6, lane = tid & 63, quad = lane >> 4, l16 = lane & 15;
  const int wm = wave >> 1, wn = wave & 1;
  const int ch0 = ks * cps;
  const int ch1 = min(nchunks, ch0 + cps);
  {
    const _Float16* src = h5h + (size_t)mblk * 64 * 320;
    for (int u = tid; u < 64 * 41; u += 256) {
      int r = u / 41, c8 = u - r * 41;
      h8 v8 = {0, 0, 0, 0, 0, 0, 0, 0};
      if (c8 < 40) v8 = *(const h8*)&src[r * 320 + c8 * 8];
      *(h8*)&h5L[r][c8 * 8] = v8;
    }
    for (int u = tid; u < 200; u += 256)
      metaL[u] = (u < cps && ch0 + u < nchunks) ? meta[ch0 + u] : 0;
  }
  __syncthreads();

  f4 acc[2][5];
  #pragma unroll
  for (int i = 0; i < 2; i++)
    #pragma unroll
    for (int j = 0; j < 5; j++) acc[i][j] = (f4){0.f, 0.f, 0.f, 0.f};

  const _Float16* wbase = Wgf + ((size_t)(nblk * 10 + wn * 5) * 64 + lane) * 8;
  h8 bA[5], bB[5];
  #define LOADB(DST, CH)                                                       \
    _Pragma("unroll")                                                          \
    for (int nt = 0; nt < 5; nt++)                                             \
      DST[nt] = *(const h8*)&wbase[(size_t)(CH) * 10240 + nt * 512];

  if (ch0 < ch1) { LOADB(bA, ch0); }
  if (ch0 + 1 < ch1) { LOADB(bB, ch0 + 1); }

  _Float16 hi[2];
  int iiprev = -1;

  auto step = [&](int ch, h8* bf) {
    const int mt = metaL[ch - ch0];
    const int ii = mt & 0xffff, j0 = mt >> 16;
    if (ii != iiprev) {
      #pragma unroll
      for (int mi = 0; mi < 2; mi++) hi[mi] = h5L[wm * 32 + mi * 16 + l16][ii];
      iiprev = ii;
    }
    h8 af[2];
    #pragma unroll
    for (int mi = 0; mi < 2; mi++) {
      h8 vj = *(const h8*)&h5L[wm * 32 + mi * 16 + l16][j0 + quad * 8];
      _Float16 h = hi[mi];
      h8 hs = {h, h, h, h, h, h, h, h};
      af[mi] = vj * hs;
    }
    #pragma unroll
    for (int mi = 0; mi < 2; mi++)
      #pragma unroll
      for (int nt = 0; nt < 5; nt++)
        acc[mi][nt] = __builtin_amdgcn_mfma_f32_16x16x32_f16(af[mi], bf[nt], acc[mi][nt], 0, 0, 0);
  };

  int ch = ch0;
  while (ch < ch1) {
    step(ch, bA);
    if (ch + 2 < ch1) { LOADB(bA, ch + 2); }
    ch++;
    if (ch < ch1) {
      step(ch, bB);
      if (ch + 2 < ch1) { LOADB(bB, ch + 2); }
      ch++;
    }
  }
  #undef LOADB

  float* dst = part + (size_t)ks * (B_ * E_);
  #pragma unroll
  for (int mi = 0; mi < 2; mi++) {
    int b = mblk * 64 + wm * 32 + mi * 16 + quad * 4;
    #pragma unroll
    for (int nt = 0; nt < 5; nt++) {
      int e = nblk * 160 + wn * 80 + nt * 16 + l16;
      if (e < E_) {
        #pragma unroll
        for (int r = 0; r < 4; r++)
          dst[(size_t)(b + r) * E_ + e] = acc[mi][nt][r];
      }
    }
  }
}

extern "C" void kernel_launch(void* const* d_in, const int* in_sizes, int n_in,
                              void* d_out, int out_size, void* d_ws, size_t ws_size,
                              hipStream_t stream) {
  const float* x    = (const float*)d_in[0];
  const float* lemb = (const float*)d_in[1];
  const float* fc1w = (const float*)d_in[2];
  const float* fc1b = (const float*)d_in[3];
  const float* q1   = (const float*)d_in[4];
  const float* fc3w = (const float*)d_in[5];
  const float* fc3b = (const float*)d_in[6];
  const float* q2   = (const float*)d_in[7];
  const float* fc5w = (const float*)d_in[8];
  const float* fc6w = (const float*)d_in[10];
  const float* fc7w = (const float*)d_in[12];
  const float* fc8w = (const float*)d_in[14];
  const float* fc8b = (const float*)d_in[15];
  const float* v    = (const float*)d_in[16];
  float* out = (float*)d_out;
  (void)in_sizes; (void)n_in; (void)out_size; (void)ws_size;

  // chunk enumeration (host-side): nchunks = 1586
  int nchunks = 0;
  for (int i = 0; i < 299; i++) { int js = (i + 1) & ~7; nchunks += (300 - js + 31) >> 5; }
  int cps = (nchunks + KSPLIT - 1) / KSPLIT;   // 199

  char* base = (char*)d_ws;
  size_t off = 0;
  auto alloc = [&](size_t nbytes) -> char* {
    char* p = base + off;
    off = (off + nbytes + 255) & ~(size_t)255;
    return p;
  };
  int*       meta  = (int*)      alloc((size_t)nchunks * 4);
  _Float16*  Wgf   = (_Float16*) alloc((size_t)nchunks * 20 * 64 * 8 * 2);  // 32.5 MB
  _Float16*  Wf5   = (_Float16*) alloc((size_t)19 * 19 * 512 * 2);
  _Float16*  Wf6   = (_Float16*) alloc((size_t)10 * 19 * 512 * 2);
  _Float16*  Wf8   = (_Float16*) alloc((size_t)19 * 19 * 512 * 2);
  _Float16*  WfL   = (_Float16*) alloc((size_t)10 * 63 * 512 * 2);
  _Float16*  hh    = (_Float16*) alloc((size_t)B_ * 608 * 2);
  _Float16*  h5h   = (_Float16*) alloc((size_t)B_ * 320 * 2);
  _Float16*  hcath = (_Float16*) alloc((size_t)B_ * 608 * 2);
  _Float16*  out8h = (_Float16*) alloc((size_t)B_ * 320 * 2);
  float*     pre   = (float*)    alloc((size_t)B_ * E_ * 4);   // shared h5pre/h6pre/h7pre
  float*     cpart = (float*)    alloc((size_t)64 * E_ * 2 * 4);
  float*     cstat = (float*)    alloc((size_t)E_ * 2 * 4);
  size_t part_bytes = (size_t)KSPLIT * B_ * E_ * 4;            // 19.66 MB
  char* scratch = alloc(part_bytes);
  float* a     = (float*)scratch;                              // [R_][16] 6.55 MB (phase 1)
  float* sabs  = a + (size_t)R_ * 16;
  float* sstat = sabs + R_;
  float* part  = (float*)scratch;                              // reused after k_pool

  // prep: metadata + all weight conversions
  hipLaunchKernelGGL(k_meta, dim3(1), dim3(320), 0, stream, meta);
  hipLaunchKernelGGL(k_wg3, dim3(nchunks, 5), dim3(256), 0, stream, fc7w, v, meta, Wgf);
  hipLaunchKernelGGL(k_wf, dim3(19, 5), dim3(256), 0, stream, fc5w, Wf5, 300, 600, 19);
  hipLaunchKernelGGL(k_wf, dim3(10, 5), dim3(256), 0, stream, fc6w, Wf6, 300, 300, 19);
  hipLaunchKernelGGL(k_wf, dim3(19, 5), dim3(256), 0, stream, fc8w, Wf8, 300, 600, 19);
  hipLaunchKernelGGL(k_wf, dim3(10, 16), dim3(256), 0, stream, lemb, WfL, 1000, 300, 63);
  // attention pools
  hipLaunchKernelGGL(k_attn2, dim3(R_ / 128), dim3(256), 0, stream, x, fc1w, fc1b, fc3w, fc3b, a, sabs);
  hipLaunchKernelGGL(k_attnstats, dim3(S_, 2), dim3(256), 0, stream, a, sstat);
  hipLaunchKernelGGL(k_pool, dim3(B_), dim3(256), 0, stream, x, a, sabs, sstat, q1, q2, hh);
  // fc5 (f16 MFMA, ksplit 4) + BN -> h5h
  hipLaunchKernelGGL(k_gemmf, dim3(32, 2, 4), dim3(256), 0, stream, hh, 608, Wf5, 19, part, 300, 19, 5);
  hipLaunchKernelGGL(k_reduce_stat, dim3(64), dim3(256), 0, stream, part, pre, cpart, 4);
  hipLaunchKernelGGL(k_colstat_fin, dim3(1), dim3(320), 0, stream, cpart, cstat, E_, 64, B_);
  hipLaunchKernelGGL(k_norm_h5h, dim3((B_ * 320) / 256), dim3(256), 0, stream, pre, cstat, h5h);
  // fc6 + BN -> hcath[:, :300]
  hipLaunchKernelGGL(k_gemmf, dim3(32, 2, 4), dim3(256), 0, stream, h5h, 320, Wf6, 19, part, 300, 10, 3);
  hipLaunchKernelGGL(k_reduce_stat, dim3(64), dim3(256), 0, stream, part, pre, cpart, 4);
  hipLaunchKernelGGL(k_colstat_fin, dim3(1), dim3(320), 0, stream, cpart, cstat, E_, 64, B_);
  hipLaunchKernelGGL(k_norm_hcat, dim3((B_ * 300 + 255) / 256), dim3(256), 0, stream, pre, cstat, hcath, 0, 0);
  // cross-feature GEMM + BN -> hcath[:, 300:] (+pad)
  hipLaunchKernelGGL(k_bigmm4, dim3(KSPLIT, 32, 2), dim3(256), 0, stream, Wgf, h5h, meta, part, nchunks, cps);
  hipLaunchKernelGGL(k_reduce_stat, dim3(64), dim3(256), 0, stream, part, pre, cpart, 8);
  hipLaunchKernelGGL(k_colstat_fin, dim3(1), dim3(320), 0, stream, cpart, cstat, E_, 64, B_);
  hipLaunchKernelGGL(k_norm_hcat, dim3((B_ * 308 + 255) / 256), dim3(256), 0, stream, pre, cstat, hcath, 300, 8);
  // fc8 (ksplit 4) + bias -> out8h f16
  hipLaunchKernelGGL(k_gemmf, dim3(32, 2, 4), dim3(256), 0, stream, hcath, 608, Wf8, 19, part, 300, 19, 5);
  hipLaunchKernelGGL(k_redbias_h, dim3((B_ * 320) / 256), dim3(256), 0, stream, part, fc8b, out8h);
  // label projection (direct f32 out)
  hipLaunchKernelGGL(k_gemmf, dim3(32, 7, 1), dim3(256), 0, stream, out8h, 320, WfL, 63, out, 1000, 10, 10);
}